// Round 6
// baseline (854.842 us; speedup 1.0000x reference)
//
#include <hip/hip_runtime.h>
#include <math.h>

#define NB    32
#define SEQ   512
#define INF_  128
#define NH    8
#define HD    16
#define NEGV  (-1e9f)
#define SCALE_ 0.25f

// ---------------- DPP wave64 primitives ----------------
template<int CTRL>
__device__ __forceinline__ float dpp_max_step(float x){
  int xi = __float_as_int(x);
  int yi = __builtin_amdgcn_update_dpp(xi, xi, CTRL, 0xF, 0xF, false);
  return fmaxf(x, __int_as_float(yi));
}
// max over all 64 lanes, result broadcast via SGPR (readlane 63)
__device__ __forceinline__ float wave_max_all(float x){
  x = dpp_max_step<0x111>(x);   // row_shr:1
  x = dpp_max_step<0x112>(x);   // row_shr:2
  x = dpp_max_step<0x114>(x);   // row_shr:4
  x = dpp_max_step<0x118>(x);   // row_shr:8
  x = dpp_max_step<0x142>(x);   // row_bcast:15 (old=self -> safe unmasked for max)
  x = dpp_max_step<0x143>(x);   // row_bcast:31
  return __int_as_float(__builtin_amdgcn_readlane(__float_as_int(x), 63));
}
template<int CTRL, int ROWMASK>
__device__ __forceinline__ int dpp_add_step(int x){
  int y = __builtin_amdgcn_update_dpp(0, x, CTRL, ROWMASK, 0xF, false);
  return x + y;
}
// inclusive prefix sum across 64 lanes (canonical GCN scan: bcast15 rows 1,3; bcast31 rows 2,3)
__device__ __forceinline__ int wave_iscan(int x){
  x = dpp_add_step<0x111, 0xF>(x);
  x = dpp_add_step<0x112, 0xF>(x);
  x = dpp_add_step<0x114, 0xF>(x);
  x = dpp_add_step<0x118, 0xF>(x);
  x = dpp_add_step<0x142, 0xa>(x);   // row_bcast:15 -> rows 1,3 only
  x = dpp_add_step<0x143, 0xc>(x);   // row_bcast:31 -> rows 2,3 only
  return x;
}
template<int CTRL>
__device__ __forceinline__ void dpp_max2_step(unsigned &hi, unsigned &lo){
  unsigned oh = (unsigned)__builtin_amdgcn_update_dpp((int)hi, (int)hi, CTRL, 0xF, 0xF, false);
  unsigned ol = (unsigned)__builtin_amdgcn_update_dpp((int)lo, (int)lo, CTRL, 0xF, 0xF, false);
  bool gt = (oh > hi) | ((oh == hi) & (ol > lo));
  hi = gt ? oh : hi;
  lo = gt ? ol : lo;
}

#define CSW(a,b) { float hi_ = fmaxf(a,b); float lo_ = fminf(a,b); a = hi_; b = lo_; }

// ---------------- Kernel 1: fused QKV projection + relu ----------------
__global__ __launch_bounds__(256) void qkv_kernel(
    const float* __restrict__ x,
    const float* __restrict__ Wq, const float* __restrict__ bq,
    const float* __restrict__ Wk, const float* __restrict__ bk,
    const float* __restrict__ Wv, const float* __restrict__ bv,
    float* __restrict__ qo, float* __restrict__ ko, float* __restrict__ vo)
{
  __shared__ float xs[32*128];
  const int tid = threadIdx.x;
  const size_t row0 = (size_t)blockIdx.x * 32;
  const float4* xg = (const float4*)(x + row0*INF_);
  float4* xs4 = (float4*)xs;
  for (int t = tid; t < 1024; t += 256) xs4[t] = xg[t];
  __syncthreads();

  const int wave = tid >> 6, lane = tid & 63;
  const int r0 = wave * 8;
  float aq0[8], aq1[8], ak0[8], ak1[8], av0[8], av1[8];
  #pragma unroll
  for (int r=0;r<8;r++){ aq0[r]=aq1[r]=ak0[r]=ak1[r]=av0[r]=av1[r]=0.f; }

  for (int kb = 0; kb < 128; kb += 4){
    float4 xv[8];
    #pragma unroll
    for (int r=0;r<8;r++) xv[r] = *(const float4*)&xs[(r0+r)*INF_ + kb];
    #pragma unroll
    for (int kk=0;kk<4;kk++){
      const int krow = (kb+kk)*INF_;
      float wq0 = Wq[krow + lane], wq1 = Wq[krow + lane + 64];
      float wk0 = Wk[krow + lane], wk1 = Wk[krow + lane + 64];
      float wv0 = Wv[krow + lane], wv1 = Wv[krow + lane + 64];
      #pragma unroll
      for (int r=0;r<8;r++){
        float xr = (kk==0)? xv[r].x : (kk==1)? xv[r].y : (kk==2)? xv[r].z : xv[r].w;
        aq0[r] = fmaf(xr, wq0, aq0[r]); aq1[r] = fmaf(xr, wq1, aq1[r]);
        ak0[r] = fmaf(xr, wk0, ak0[r]); ak1[r] = fmaf(xr, wk1, ak1[r]);
        av0[r] = fmaf(xr, wv0, av0[r]); av1[r] = fmaf(xr, wv1, av1[r]);
      }
    }
  }
  float bq0 = bq[lane], bq1 = bq[lane+64];
  float bk0_ = bk[lane], bk1_ = bk[lane+64];
  float bv0_ = bv[lane], bv1_ = bv[lane+64];
  #pragma unroll
  for (int r=0;r<8;r++){
    size_t o = (row0 + r0 + r)*INF_;
    qo[o + lane]      = fmaxf(aq0[r] + bq0, 0.f);
    qo[o + lane + 64] = fmaxf(aq1[r] + bq1, 0.f);
    ko[o + lane]      = fmaxf(ak0[r] + bk0_, 0.f);
    ko[o + lane + 64] = fmaxf(ak1[r] + bk1_, 0.f);
    vo[o + lane]      = fmaxf(av0[r] + bv0_, 0.f);
    vo[o + lane + 64] = fmaxf(av1[r] + bv1_, 0.f);
  }
}

// ---------------- Kernel 2: logits + mask + exact top-16 + softmax + PV + residual ----------------
// grid = 512 (one block per (b,h,half)); block = 512 threads (8 waves)
// LDS 73 KB -> 2 blocks/CU (16 waves/CU). Extraction runs 2 rows interleaved for ILP.
__global__ __launch_bounds__(512, 4) void attn_kernel(
    const float* __restrict__ qg, const float* __restrict__ kg, const float* __restrict__ vg,
    const int* __restrict__ mask, float* __restrict__ logits_out, float* __restrict__ att_out)
{
  __shared__ float K_lds[512*20];   // 40 KB; stride 20 -> conflict-free b128 at k = lane + 64*kk
  __shared__ float V_lds[512*16];   // 32 KB
  __shared__ float pv_s[8*16];
  __shared__ int   pi_s[8*16];

  const int tid  = threadIdx.x;
  const int bh   = blockIdx.x >> 1;
  const int split= blockIdx.x & 1;
  const int b    = bh >> 3, h = bh & 7;
  const int n0   = split * 256;
  const size_t base_bh = ((size_t)b * SEQ) * INF_ + (size_t)h * HD;

  // stage K (pad 20), V (stride 16) for all 512 rows
  for (int t = tid; t < 2048; t += 512){
    int row = t >> 2, c = t & 3;
    float4 k4 = *(const float4*)(kg + base_bh + (size_t)row*INF_ + c*4);
    *(float4*)&K_lds[row*20 + c*4] = k4;
    float4 v4 = *(const float4*)(vg + base_bh + (size_t)row*INF_ + c*4);
    *(float4*)&V_lds[row*16 + c*4] = v4;
  }
  __syncthreads();

  const int wave = tid >> 6, lane = tid & 63;
  const int wavebase = wave * 16;

  #pragma unroll 1
  for (int g = 0; g < 8; ++g){
    const int nl = wave*32 + g*4;          // block-local row base (group of 4)
    const int n  = n0 + nl;                // global row

    // mask loads issued early (latency hides under logit FMAs); compressed to 4 bitmasks after
    int mreg[4][8];
    const int* mrow = mask + ((size_t)b*SEQ + n)*SEQ + lane;
    #pragma unroll
    for (int r=0;r<4;r++)
      #pragma unroll
      for (int kk=0;kk<8;kk++)
        mreg[r][kk] = mrow[(size_t)r*SEQ + kk*64];

    // q regs: wave-uniform global loads (L1 broadcast; region is 16 KB, L1-resident)
    float4 qv[4][4];
    #pragma unroll
    for (int r=0;r<4;r++){
      const float4* qp = (const float4*)(qg + base_bh + (size_t)(n+r)*INF_);
      #pragma unroll
      for (int c=0;c<4;c++) qv[r][c] = qp[c];
    }

    // logits for 4 rows x 8 k-slots (k = lane + 64*kk)
    float acc[4][8];
    #pragma unroll
    for (int r=0;r<4;r++)
      #pragma unroll
      for (int kk=0;kk<8;kk++) acc[r][kk] = 0.f;

    #pragma unroll
    for (int kk=0;kk<8;kk++){
      const float4* Kp = (const float4*)&K_lds[(lane + kk*64)*20];
      float4 k0 = Kp[0], k1 = Kp[1], k2 = Kp[2], k3 = Kp[3];
      #pragma unroll
      for (int r=0;r<4;r++){
        float a = acc[r][kk];
        a = fmaf(qv[r][0].x, k0.x, a); a = fmaf(qv[r][0].y, k0.y, a);
        a = fmaf(qv[r][0].z, k0.z, a); a = fmaf(qv[r][0].w, k0.w, a);
        a = fmaf(qv[r][1].x, k1.x, a); a = fmaf(qv[r][1].y, k1.y, a);
        a = fmaf(qv[r][1].z, k1.z, a); a = fmaf(qv[r][1].w, k1.w, a);
        a = fmaf(qv[r][2].x, k2.x, a); a = fmaf(qv[r][2].y, k2.y, a);
        a = fmaf(qv[r][2].z, k2.z, a); a = fmaf(qv[r][2].w, k2.w, a);
        a = fmaf(qv[r][3].x, k3.x, a); a = fmaf(qv[r][3].y, k3.y, a);
        a = fmaf(qv[r][3].z, k3.z, a); a = fmaf(qv[r][3].w, k3.w, a);
        acc[r][kk] = a;
      }
    }

    // compress masks to 4 bitmasks (frees 28 VGPRs)
    int mbits[4];
    #pragma unroll
    for (int r=0;r<4;r++){
      int mb = 0;
      #pragma unroll
      for (int kk=0;kk<8;kk++) mb |= (mreg[r][kk] != 0) ? (1<<kk) : 0;
      mbits[r] = mb;
    }

    float* lbase = logits_out + (((size_t)(b*NH + h)*SEQ + n)*SEQ) + lane;

    // process rows in pairs: interleaved DPP extraction chains for ILP
    #pragma unroll
    for (int pr=0; pr<2; ++pr){
      const int rA = 2*pr, rB = 2*pr + 1;

      // scale, store logits, mask-select in place (acc becomes mv)
      #pragma unroll
      for (int kk=0;kk<8;kk++){
        float svA = acc[rA][kk] * SCALE_;
        float svB = acc[rB][kk] * SCALE_;
        lbase[(size_t)rA*SEQ + kk*64] = svA;
        lbase[(size_t)rB*SEQ + kk*64] = svB;
        acc[rA][kk] = (mbits[rA] & (1<<kk)) ? svA : NEGV;
        acc[rB][kk] = (mbits[rB] & (1<<kk)) ? svB : NEGV;
      }

      // per-lane descending sort of 8 (Batcher, 19 CE) -- both rows, straight-line
      float a0=acc[rA][0], a1=acc[rA][1], a2=acc[rA][2], a3=acc[rA][3],
            a4=acc[rA][4], a5=acc[rA][5], a6=acc[rA][6], a7=acc[rA][7];
      float b0=acc[rB][0], b1=acc[rB][1], b2=acc[rB][2], b3=acc[rB][3],
            b4=acc[rB][4], b5=acc[rB][5], b6=acc[rB][6], b7=acc[rB][7];
      CSW(a0,a1) CSW(a2,a3) CSW(a4,a5) CSW(a6,a7)
      CSW(b0,b1) CSW(b2,b3) CSW(b4,b5) CSW(b6,b7)
      CSW(a0,a2) CSW(a1,a3) CSW(a4,a6) CSW(a5,a7)
      CSW(b0,b2) CSW(b1,b3) CSW(b4,b6) CSW(b5,b7)
      CSW(a1,a2) CSW(a5,a6)
      CSW(b1,b2) CSW(b5,b6)
      CSW(a0,a4) CSW(a1,a5) CSW(a2,a6) CSW(a3,a7)
      CSW(b0,b4) CSW(b1,b5) CSW(b2,b6) CSW(b3,b7)
      CSW(a2,a4) CSW(a3,a5)
      CSW(b2,b4) CSW(b3,b5)
      CSW(a1,a2) CSW(a3,a4) CSW(a5,a6)
      CSW(b1,b2) CSW(b3,b4) CSW(b5,b6)

      // 16 rounds of dedup'd extraction, TWO independent chains interleaved
      float curA = a0, curB = b0;
      float MA = 0.f, TA = 0.f, MB = 0.f, TB = 0.f;
      #pragma unroll
      for (int it=0; it<16; ++it){
        float mA = wave_max_all(curA);
        float mB = wave_max_all(curB);
        if (it == 0){ MA = mA; MB = mB; }
        TA = mA; TB = mB;
        bool cA = (curA == mA);
        a0 = cA ? a1 : a0; a1 = cA ? a2 : a1; a2 = cA ? a3 : a2; a3 = cA ? a4 : a3;
        a4 = cA ? a5 : a4; a5 = cA ? a6 : a5; a6 = cA ? a7 : a6;
        a7 = cA ? -__builtin_inff() : a7;
        curA = a0;
        bool cB = (curB == mB);
        b0 = cB ? b1 : b0; b1 = cB ? b2 : b1; b2 = cB ? b3 : b2; b3 = cB ? b4 : b3;
        b4 = cB ? b5 : b4; b5 = cB ? b6 : b5; b6 = cB ? b7 : b6;
        b7 = cB ? -__builtin_inff() : b7;
        curB = b0;
      }

      // per-row: selection + count verification + PV + residual
      #pragma unroll
      for (int rr=0; rr<2; ++rr){
        const int r   = 2*pr + rr;
        const int n_r = n + r;
        const float T = rr ? TB : TA;
        const float M = rr ? MB : MA;

        int cnt = 0, selb = 0;
        #pragma unroll
        for (int kk=0;kk<8;kk++){
          bool s_ = (acc[r][kk] >= T);
          cnt += s_ ? 1 : 0;
          selb |= s_ ? (1<<kk) : 0;
        }
        int incl  = wave_iscan(cnt);
        int total = __builtin_amdgcn_readlane(incl, 63);
        int pos   = wavebase + (incl - cnt);

        if (total == 16){
          #pragma unroll
          for (int kk=0;kk<8;kk++){
            if (selb & (1<<kk)){
              pv_s[pos] = acc[r][kk];
              pi_s[pos] = lane + (kk<<6);
              ++pos;
            }
          }
        } else {
          // exact fallback: (value desc, index asc) — matches jax.lax.top_k tie-break
          unsigned kh[8], kl[8];
          #pragma unroll
          for (int kk=0;kk<8;kk++){
            unsigned u = (unsigned)__float_as_int(acc[r][kk]);
            u = u ^ ((u & 0x80000000u) ? 0xFFFFFFFFu : 0x80000000u);  // order-preserving map
            kh[kk] = u;
            kl[kk] = (unsigned)(511 - (lane + (kk<<6)));
          }
          for (int it=0; it<16; ++it){
            unsigned bh_ = kh[0], bl_ = kl[0];
            #pragma unroll
            for (int kk=1;kk<8;kk++){
              bool g_ = (kh[kk] > bh_) | ((kh[kk]==bh_) & (kl[kk] > bl_));
              bh_ = g_ ? kh[kk] : bh_;
              bl_ = g_ ? kl[kk] : bl_;
            }
            dpp_max2_step<0x111>(bh_, bl_);
            dpp_max2_step<0x112>(bh_, bl_);
            dpp_max2_step<0x114>(bh_, bl_);
            dpp_max2_step<0x118>(bh_, bl_);
            dpp_max2_step<0x142>(bh_, bl_);
            dpp_max2_step<0x143>(bh_, bl_);
            unsigned mh = (unsigned)__builtin_amdgcn_readlane((int)bh_, 63);
            unsigned ml = (unsigned)__builtin_amdgcn_readlane((int)bl_, 63);
            int widx = 511 - (int)ml;
            #pragma unroll
            for (int kk=0;kk<8;kk++){
              if (kh[kk]==mh && kl[kk]==ml){
                pv_s[wavebase + it] = acc[r][kk];
                pi_s[wavebase + it] = widx;
                kh[kk] = 0u; kl[kk] = 0u;
              }
            }
          }
        }

        // PV + softmax normalize + residual
        asm volatile("s_waitcnt lgkmcnt(0)" ::: "memory");
        __builtin_amdgcn_sched_barrier(0);
        const int rep = lane >> 4;
        const int d   = lane & 15;
        float o = 0.f, sp = 0.f;
        #pragma unroll
        for (int j=0;j<4;j++){
          const int i = wavebase + rep*4 + j;
          float vv = pv_s[i];
          int  idx = pi_s[i];
          float p = __expf(vv - M);
          o  = fmaf(p, V_lds[idx*16 + d], o);
          sp += p;
        }
        o  += __shfl_xor(o, 16);
        o  += __shfl_xor(o, 32);
        sp += __shfl_xor(sp, 16);
        sp += __shfl_xor(sp, 32);
        float res = o / sp + V_lds[n_r*16 + d];
        if (lane < 16)
          att_out[((size_t)b*SEQ + n_r)*INF_ + (size_t)h*HD + d] = res;
      }
    }
  }
}

// ---------------- Kernel 3: output projection + relu ----------------
__global__ __launch_bounds__(256) void out_kernel(
    const float* __restrict__ a, const float* __restrict__ W, const float* __restrict__ bias,
    float* __restrict__ out)
{
  __shared__ float xs[32*128];
  const int tid = threadIdx.x;
  const size_t row0 = (size_t)blockIdx.x * 32;
  const float4* ag = (const float4*)(a + row0*INF_);
  float4* xs4 = (float4*)xs;
  for (int t = tid; t < 1024; t += 256) xs4[t] = ag[t];
  __syncthreads();

  const int wave = tid >> 6, lane = tid & 63;
  const int r0 = wave * 8;
  float a0[8], a1[8];
  #pragma unroll
  for (int r=0;r<8;r++){ a0[r]=a1[r]=0.f; }

  for (int kb = 0; kb < 128; kb += 4){
    float4 xv[8];
    #pragma unroll
    for (int r=0;r<8;r++) xv[r] = *(const float4*)&xs[(r0+r)*INF_ + kb];
    #pragma unroll
    for (int kk=0;kk<4;kk++){
      const int krow = (kb+kk)*INF_;
      float w0 = W[krow + lane], w1 = W[krow + lane + 64];
      #pragma unroll
      for (int r=0;r<8;r++){
        float xr = (kk==0)? xv[r].x : (kk==1)? xv[r].y : (kk==2)? xv[r].z : xv[r].w;
        a0[r] = fmaf(xr, w0, a0[r]);
        a1[r] = fmaf(xr, w1, a1[r]);
      }
    }
  }
  float b0 = bias[lane], b1 = bias[lane+64];
  #pragma unroll
  for (int r=0;r<8;r++){
    size_t o = (row0 + r0 + r)*INF_;
    out[o + lane]      = fmaxf(a0[r] + b0, 0.f);
    out[o + lane + 64] = fmaxf(a1[r] + b1, 0.f);
  }
}

extern "C" void kernel_launch(void* const* d_in, const int* in_sizes, int n_in,
                              void* d_out, int out_size, void* d_ws, size_t ws_size,
                              hipStream_t stream)
{
  const float* x    = (const float*)d_in[0];
  const int*   mask = (const int*)  d_in[1];
  const float* Wq   = (const float*)d_in[2];
  const float* bq   = (const float*)d_in[3];
  const float* Wk   = (const float*)d_in[4];
  const float* bk   = (const float*)d_in[5];
  const float* Wv   = (const float*)d_in[6];
  const float* bv   = (const float*)d_in[7];
  const float* Wout = (const float*)d_in[8];
  const float* bout = (const float*)d_in[9];

  float* out_f  = (float*)d_out;
  float* logits = out_f + (size_t)NB*SEQ*INF_;          // att_logits region of d_out

  float* qws = (float*)d_ws;                            // [B,N,128] each, f32
  float* kws = qws + (size_t)NB*SEQ*INF_;
  float* vws = kws + (size_t)NB*SEQ*INF_;
  float* aws = vws + (size_t)NB*SEQ*INF_;               // att_out [B,N,H*DV]

  qkv_kernel<<<512, 256, 0, stream>>>(x, Wq,bq, Wk,bk, Wv,bv, qws, kws, vws);
  attn_kernel<<<512, 512, 0, stream>>>(qws, kws, vws, mask, logits, aws);
  out_kernel<<<512, 256, 0, stream>>>(aws, Wout, bout, out_f);
}

// Round 7
// 526.254 us; speedup vs baseline: 1.6244x; 1.6244x over previous
//
#include <hip/hip_runtime.h>
#include <math.h>

#define NB    32
#define SEQ   512
#define INF_  128
#define NH    8
#define HD    16
#define NEGV  (-1e9f)
#define SCALE_ 0.25f

// ---------------- DPP wave64 primitives ----------------
template<int CTRL>
__device__ __forceinline__ float dpp_max_step(float x){
  int xi = __float_as_int(x);
  int yi = __builtin_amdgcn_update_dpp(xi, xi, CTRL, 0xF, 0xF, false);
  return fmaxf(x, __int_as_float(yi));
}
// max over all 64 lanes, result broadcast via SGPR (readlane 63)
__device__ __forceinline__ float wave_max_all(float x){
  x = dpp_max_step<0x111>(x);   // row_shr:1
  x = dpp_max_step<0x112>(x);   // row_shr:2
  x = dpp_max_step<0x114>(x);   // row_shr:4
  x = dpp_max_step<0x118>(x);   // row_shr:8
  x = dpp_max_step<0x142>(x);   // row_bcast:15 (old=self -> safe unmasked for max)
  x = dpp_max_step<0x143>(x);   // row_bcast:31
  return __int_as_float(__builtin_amdgcn_readlane(__float_as_int(x), 63));
}
template<int CTRL, int ROWMASK>
__device__ __forceinline__ int dpp_add_step(int x){
  int y = __builtin_amdgcn_update_dpp(0, x, CTRL, ROWMASK, 0xF, false);
  return x + y;
}
// inclusive prefix sum across 64 lanes (canonical GCN scan: bcast15 rows 1,3; bcast31 rows 2,3)
__device__ __forceinline__ int wave_iscan(int x){
  x = dpp_add_step<0x111, 0xF>(x);
  x = dpp_add_step<0x112, 0xF>(x);
  x = dpp_add_step<0x114, 0xF>(x);
  x = dpp_add_step<0x118, 0xF>(x);
  x = dpp_add_step<0x142, 0xa>(x);   // row_bcast:15 -> rows 1,3 only
  x = dpp_add_step<0x143, 0xc>(x);   // row_bcast:31 -> rows 2,3 only
  return x;
}
template<int CTRL>
__device__ __forceinline__ void dpp_max2_step(unsigned &hi, unsigned &lo){
  unsigned oh = (unsigned)__builtin_amdgcn_update_dpp((int)hi, (int)hi, CTRL, 0xF, 0xF, false);
  unsigned ol = (unsigned)__builtin_amdgcn_update_dpp((int)lo, (int)lo, CTRL, 0xF, 0xF, false);
  bool gt = (oh > hi) | ((oh == hi) & (ol > lo));
  hi = gt ? oh : hi;
  lo = gt ? ol : lo;
}

#define CSW(a,b) { float hi_ = fmaxf(a,b); float lo_ = fminf(a,b); a = hi_; b = lo_; }

// ---------------- Kernel 1: fused QKV projection + relu ----------------
__global__ __launch_bounds__(256) void qkv_kernel(
    const float* __restrict__ x,
    const float* __restrict__ Wq, const float* __restrict__ bq,
    const float* __restrict__ Wk, const float* __restrict__ bk,
    const float* __restrict__ Wv, const float* __restrict__ bv,
    float* __restrict__ qo, float* __restrict__ ko, float* __restrict__ vo)
{
  __shared__ float xs[32*128];
  const int tid = threadIdx.x;
  const size_t row0 = (size_t)blockIdx.x * 32;
  const float4* xg = (const float4*)(x + row0*INF_);
  float4* xs4 = (float4*)xs;
  for (int t = tid; t < 1024; t += 256) xs4[t] = xg[t];
  __syncthreads();

  const int wave = tid >> 6, lane = tid & 63;
  const int r0 = wave * 8;
  float aq0[8], aq1[8], ak0[8], ak1[8], av0[8], av1[8];
  #pragma unroll
  for (int r=0;r<8;r++){ aq0[r]=aq1[r]=ak0[r]=ak1[r]=av0[r]=av1[r]=0.f; }

  for (int kb = 0; kb < 128; kb += 4){
    float4 xv[8];
    #pragma unroll
    for (int r=0;r<8;r++) xv[r] = *(const float4*)&xs[(r0+r)*INF_ + kb];
    #pragma unroll
    for (int kk=0;kk<4;kk++){
      const int krow = (kb+kk)*INF_;
      float wq0 = Wq[krow + lane], wq1 = Wq[krow + lane + 64];
      float wk0 = Wk[krow + lane], wk1 = Wk[krow + lane + 64];
      float wv0 = Wv[krow + lane], wv1 = Wv[krow + lane + 64];
      #pragma unroll
      for (int r=0;r<8;r++){
        float xr = (kk==0)? xv[r].x : (kk==1)? xv[r].y : (kk==2)? xv[r].z : xv[r].w;
        aq0[r] = fmaf(xr, wq0, aq0[r]); aq1[r] = fmaf(xr, wq1, aq1[r]);
        ak0[r] = fmaf(xr, wk0, ak0[r]); ak1[r] = fmaf(xr, wk1, ak1[r]);
        av0[r] = fmaf(xr, wv0, av0[r]); av1[r] = fmaf(xr, wv1, av1[r]);
      }
    }
  }
  float bq0 = bq[lane], bq1 = bq[lane+64];
  float bk0_ = bk[lane], bk1_ = bk[lane+64];
  float bv0_ = bv[lane], bv1_ = bv[lane+64];
  #pragma unroll
  for (int r=0;r<8;r++){
    size_t o = (row0 + r0 + r)*INF_;
    qo[o + lane]      = fmaxf(aq0[r] + bq0, 0.f);
    qo[o + lane + 64] = fmaxf(aq1[r] + bq1, 0.f);
    ko[o + lane]      = fmaxf(ak0[r] + bk0_, 0.f);
    ko[o + lane + 64] = fmaxf(ak1[r] + bk1_, 0.f);
    vo[o + lane]      = fmaxf(av0[r] + bv0_, 0.f);
    vo[o + lane + 64] = fmaxf(av1[r] + bv1_, 0.f);
  }
}

// ---------------- Kernel 2: logits + mask + exact top-16 + softmax + PV + residual ----------------
// grid = 512 (one block per (b,h,half)); block = 512 threads (8 waves)
// LDS 73 KB -> 2 blocks/CU. R=2 rows/group keeps live set ~100 VGPR (no spill; R6's
// __launch_bounds__(512,4) forced a 64-VGPR cap -> 1.7 GB scratch traffic, 2.2x slower).
__global__ __launch_bounds__(512, 2) void attn_kernel(
    const float* __restrict__ qg, const float* __restrict__ kg, const float* __restrict__ vg,
    const int* __restrict__ mask, float* __restrict__ logits_out, float* __restrict__ att_out)
{
  __shared__ float K_lds[512*20];   // 40 KB; stride 20 -> low-conflict b128 at k = lane + 64*kk
  __shared__ float V_lds[512*16];   // 32 KB
  __shared__ float pv_s[8*16];
  __shared__ int   pi_s[8*16];

  const int tid  = threadIdx.x;
  const int bh   = blockIdx.x >> 1;
  const int split= blockIdx.x & 1;
  const int b    = bh >> 3, h = bh & 7;
  const int n0   = split * 256;
  const size_t base_bh = ((size_t)b * SEQ) * INF_ + (size_t)h * HD;

  // stage K (pad 20), V (stride 16) for all 512 rows
  for (int t = tid; t < 2048; t += 512){
    int row = t >> 2, c = t & 3;
    float4 k4 = *(const float4*)(kg + base_bh + (size_t)row*INF_ + c*4);
    *(float4*)&K_lds[row*20 + c*4] = k4;
    float4 v4 = *(const float4*)(vg + base_bh + (size_t)row*INF_ + c*4);
    *(float4*)&V_lds[row*16 + c*4] = v4;
  }
  __syncthreads();

  const int wave = tid >> 6, lane = tid & 63;
  const int wavebase = wave * 16;

  #pragma unroll 1
  for (int g = 0; g < 16; ++g){
    const int nl = wave*32 + g*2;          // block-local row pair
    const int n  = n0 + nl;                // global row

    // mask loads issued early (latency hides under logit FMAs)
    int mreg[2][8];
    const int* mrow = mask + ((size_t)b*SEQ + n)*SEQ + lane;
    #pragma unroll
    for (int r=0;r<2;r++)
      #pragma unroll
      for (int kk=0;kk<8;kk++)
        mreg[r][kk] = mrow[(size_t)r*SEQ + kk*64];

    // q regs: lane-uniform global loads (L1 broadcast)
    float4 qv[2][4];
    #pragma unroll
    for (int r=0;r<2;r++){
      const float4* qp = (const float4*)(qg + base_bh + (size_t)(n+r)*INF_);
      #pragma unroll
      for (int c=0;c<4;c++) qv[r][c] = qp[c];
    }

    // logits for 2 rows x 8 k-slots (k = lane + 64*kk)
    float acc[2][8];
    #pragma unroll
    for (int r=0;r<2;r++)
      #pragma unroll
      for (int kk=0;kk<8;kk++) acc[r][kk] = 0.f;

    #pragma unroll
    for (int kk=0;kk<8;kk++){
      const float4* Kp = (const float4*)&K_lds[(lane + kk*64)*20];
      float4 k0 = Kp[0], k1 = Kp[1], k2 = Kp[2], k3 = Kp[3];
      #pragma unroll
      for (int r=0;r<2;r++){
        float a = acc[r][kk];
        a = fmaf(qv[r][0].x, k0.x, a); a = fmaf(qv[r][0].y, k0.y, a);
        a = fmaf(qv[r][0].z, k0.z, a); a = fmaf(qv[r][0].w, k0.w, a);
        a = fmaf(qv[r][1].x, k1.x, a); a = fmaf(qv[r][1].y, k1.y, a);
        a = fmaf(qv[r][1].z, k1.z, a); a = fmaf(qv[r][1].w, k1.w, a);
        a = fmaf(qv[r][2].x, k2.x, a); a = fmaf(qv[r][2].y, k2.y, a);
        a = fmaf(qv[r][2].z, k2.z, a); a = fmaf(qv[r][2].w, k2.w, a);
        a = fmaf(qv[r][3].x, k3.x, a); a = fmaf(qv[r][3].y, k3.y, a);
        a = fmaf(qv[r][3].z, k3.z, a); a = fmaf(qv[r][3].w, k3.w, a);
        acc[r][kk] = a;
      }
    }

    // compress masks to bitmasks (frees the mreg registers)
    int mb0 = 0, mb1 = 0;
    #pragma unroll
    for (int kk=0;kk<8;kk++){
      mb0 |= (mreg[0][kk] != 0) ? (1<<kk) : 0;
      mb1 |= (mreg[1][kk] != 0) ? (1<<kk) : 0;
    }

    float* lbase = logits_out + (((size_t)(b*NH + h)*SEQ + n)*SEQ) + lane;

    // scale, store logits, mask-select in place (acc becomes masked values)
    #pragma unroll
    for (int kk=0;kk<8;kk++){
      float svA = acc[0][kk] * SCALE_;
      float svB = acc[1][kk] * SCALE_;
      lbase[kk*64]               = svA;
      lbase[(size_t)SEQ + kk*64] = svB;
      acc[0][kk] = (mb0 & (1<<kk)) ? svA : NEGV;
      acc[1][kk] = (mb1 & (1<<kk)) ? svB : NEGV;
    }

    // per-lane descending sort of 8 (Batcher, 19 CE) -- both rows, straight-line
    float a0=acc[0][0], a1=acc[0][1], a2=acc[0][2], a3=acc[0][3],
          a4=acc[0][4], a5=acc[0][5], a6=acc[0][6], a7=acc[0][7];
    float b0=acc[1][0], b1=acc[1][1], b2=acc[1][2], b3=acc[1][3],
          b4=acc[1][4], b5=acc[1][5], b6=acc[1][6], b7=acc[1][7];
    CSW(a0,a1) CSW(a2,a3) CSW(a4,a5) CSW(a6,a7)
    CSW(b0,b1) CSW(b2,b3) CSW(b4,b5) CSW(b6,b7)
    CSW(a0,a2) CSW(a1,a3) CSW(a4,a6) CSW(a5,a7)
    CSW(b0,b2) CSW(b1,b3) CSW(b4,b6) CSW(b5,b7)
    CSW(a1,a2) CSW(a5,a6)
    CSW(b1,b2) CSW(b5,b6)
    CSW(a0,a4) CSW(a1,a5) CSW(a2,a6) CSW(a3,a7)
    CSW(b0,b4) CSW(b1,b5) CSW(b2,b6) CSW(b3,b7)
    CSW(a2,a4) CSW(a3,a5)
    CSW(b2,b4) CSW(b3,b5)
    CSW(a1,a2) CSW(a3,a4) CSW(a5,a6)
    CSW(b1,b2) CSW(b3,b4) CSW(b5,b6)

    // 16 rounds of dedup'd extraction, TWO independent chains interleaved
    float curA = a0, curB = b0;
    float MA = 0.f, TA = 0.f, MB = 0.f, TB = 0.f;
    #pragma unroll
    for (int it=0; it<16; ++it){
      float mA = wave_max_all(curA);
      float mB = wave_max_all(curB);
      if (it == 0){ MA = mA; MB = mB; }
      TA = mA; TB = mB;
      bool cA = (curA == mA);
      a0 = cA ? a1 : a0; a1 = cA ? a2 : a1; a2 = cA ? a3 : a2; a3 = cA ? a4 : a3;
      a4 = cA ? a5 : a4; a5 = cA ? a6 : a5; a6 = cA ? a7 : a6;
      a7 = cA ? -__builtin_inff() : a7;
      curA = a0;
      bool cB = (curB == mB);
      b0 = cB ? b1 : b0; b1 = cB ? b2 : b1; b2 = cB ? b3 : b2; b3 = cB ? b4 : b3;
      b4 = cB ? b5 : b4; b5 = cB ? b6 : b5; b6 = cB ? b7 : b6;
      b7 = cB ? -__builtin_inff() : b7;
      curB = b0;
    }

    // per-row: selection + count verification + PV + residual
    #pragma unroll
    for (int rr=0; rr<2; ++rr){
      const int n_r = n + rr;
      const float T = rr ? TB : TA;
      const float M = rr ? MB : MA;

      int cnt = 0, selb = 0;
      #pragma unroll
      for (int kk=0;kk<8;kk++){
        bool s_ = (acc[rr][kk] >= T);
        cnt += s_ ? 1 : 0;
        selb |= s_ ? (1<<kk) : 0;
      }
      int incl  = wave_iscan(cnt);
      int total = __builtin_amdgcn_readlane(incl, 63);
      int pos   = wavebase + (incl - cnt);

      if (total == 16){
        #pragma unroll
        for (int kk=0;kk<8;kk++){
          if (selb & (1<<kk)){
            pv_s[pos] = acc[rr][kk];
            pi_s[pos] = lane + (kk<<6);
            ++pos;
          }
        }
      } else {
        // exact fallback: (value desc, index asc) — matches jax.lax.top_k tie-break
        unsigned kh[8], kl[8];
        #pragma unroll
        for (int kk=0;kk<8;kk++){
          unsigned u = (unsigned)__float_as_int(acc[rr][kk]);
          u = u ^ ((u & 0x80000000u) ? 0xFFFFFFFFu : 0x80000000u);  // order-preserving map
          kh[kk] = u;
          kl[kk] = (unsigned)(511 - (lane + (kk<<6)));
        }
        for (int it=0; it<16; ++it){
          unsigned bh_ = kh[0], bl_ = kl[0];
          #pragma unroll
          for (int kk=1;kk<8;kk++){
            bool g_ = (kh[kk] > bh_) | ((kh[kk]==bh_) & (kl[kk] > bl_));
            bh_ = g_ ? kh[kk] : bh_;
            bl_ = g_ ? kl[kk] : bl_;
          }
          dpp_max2_step<0x111>(bh_, bl_);
          dpp_max2_step<0x112>(bh_, bl_);
          dpp_max2_step<0x114>(bh_, bl_);
          dpp_max2_step<0x118>(bh_, bl_);
          dpp_max2_step<0x142>(bh_, bl_);
          dpp_max2_step<0x143>(bh_, bl_);
          unsigned mh = (unsigned)__builtin_amdgcn_readlane((int)bh_, 63);
          unsigned ml = (unsigned)__builtin_amdgcn_readlane((int)bl_, 63);
          int widx = 511 - (int)ml;
          #pragma unroll
          for (int kk=0;kk<8;kk++){
            if (kh[kk]==mh && kl[kk]==ml){
              pv_s[wavebase + it] = acc[rr][kk];
              pi_s[wavebase + it] = widx;
              kh[kk] = 0u; kl[kk] = 0u;
            }
          }
        }
      }

      // PV + softmax normalize + residual
      asm volatile("s_waitcnt lgkmcnt(0)" ::: "memory");
      __builtin_amdgcn_sched_barrier(0);
      const int rep = lane >> 4;
      const int d   = lane & 15;
      float o = 0.f, sp = 0.f;
      #pragma unroll
      for (int j=0;j<4;j++){
        const int i = wavebase + rep*4 + j;
        float vv = pv_s[i];
        int  idx = pi_s[i];
        float p = __expf(vv - M);
        o  = fmaf(p, V_lds[idx*16 + d], o);
        sp += p;
      }
      o  += __shfl_xor(o, 16);
      o  += __shfl_xor(o, 32);
      sp += __shfl_xor(sp, 16);
      sp += __shfl_xor(sp, 32);
      float res = o / sp + V_lds[n_r*16 + d];
      if (lane < 16)
        att_out[((size_t)b*SEQ + n_r)*INF_ + (size_t)h*HD + d] = res;
    }
  }
}

// ---------------- Kernel 3: output projection + relu ----------------
__global__ __launch_bounds__(256) void out_kernel(
    const float* __restrict__ a, const float* __restrict__ W, const float* __restrict__ bias,
    float* __restrict__ out)
{
  __shared__ float xs[32*128];
  const int tid = threadIdx.x;
  const size_t row0 = (size_t)blockIdx.x * 32;
  const float4* ag = (const float4*)(a + row0*INF_);
  float4* xs4 = (float4*)xs;
  for (int t = tid; t < 1024; t += 256) xs4[t] = ag[t];
  __syncthreads();

  const int wave = tid >> 6, lane = tid & 63;
  const int r0 = wave * 8;
  float a0[8], a1[8];
  #pragma unroll
  for (int r=0;r<8;r++){ a0[r]=a1[r]=0.f; }

  for (int kb = 0; kb < 128; kb += 4){
    float4 xv[8];
    #pragma unroll
    for (int r=0;r<8;r++) xv[r] = *(const float4*)&xs[(r0+r)*INF_ + kb];
    #pragma unroll
    for (int kk=0;kk<4;kk++){
      const int krow = (kb+kk)*INF_;
      float w0 = W[krow + lane], w1 = W[krow + lane + 64];
      #pragma unroll
      for (int r=0;r<8;r++){
        float xr = (kk==0)? xv[r].x : (kk==1)? xv[r].y : (kk==2)? xv[r].z : xv[r].w;
        a0[r] = fmaf(xr, w0, a0[r]);
        a1[r] = fmaf(xr, w1, a1[r]);
      }
    }
  }
  float b0 = bias[lane], b1 = bias[lane+64];
  #pragma unroll
  for (int r=0;r<8;r++){
    size_t o = (row0 + r0 + r)*INF_;
    out[o + lane]      = fmaxf(a0[r] + b0, 0.f);
    out[o + lane + 64] = fmaxf(a1[r] + b1, 0.f);
  }
}

extern "C" void kernel_launch(void* const* d_in, const int* in_sizes, int n_in,
                              void* d_out, int out_size, void* d_ws, size_t ws_size,
                              hipStream_t stream)
{
  const float* x    = (const float*)d_in[0];
  const int*   mask = (const int*)  d_in[1];
  const float* Wq   = (const float*)d_in[2];
  const float* bq   = (const float*)d_in[3];
  const float* Wk   = (const float*)d_in[4];
  const float* bk   = (const float*)d_in[5];
  const float* Wv   = (const float*)d_in[6];
  const float* bv   = (const float*)d_in[7];
  const float* Wout = (const float*)d_in[8];
  const float* bout = (const float*)d_in[9];

  float* out_f  = (float*)d_out;
  float* logits = out_f + (size_t)NB*SEQ*INF_;          // att_logits region of d_out

  float* qws = (float*)d_ws;                            // [B,N,128] each, f32
  float* kws = qws + (size_t)NB*SEQ*INF_;
  float* vws = kws + (size_t)NB*SEQ*INF_;
  float* aws = vws + (size_t)NB*SEQ*INF_;               // att_out [B,N,H*DV]

  qkv_kernel<<<512, 256, 0, stream>>>(x, Wq,bq, Wk,bk, Wv,bv, qws, kws, vws);
  attn_kernel<<<512, 512, 0, stream>>>(qws, kws, vws, mask, logits, aws);
  out_kernel<<<512, 256, 0, stream>>>(aws, Wout, bout, out_f);
}